// Round 5
// baseline (302.950 us; speedup 1.0000x reference)
//
#include <hip/hip_runtime.h>

// PETP_Quadratic R8: guaranteed 2-blocks/CU residency.
//   Model corrections from R7: (1) usable LDS/CU ~= 128 KB (R5/R6/R7 occupancy
//   evidence) -> block LDS must be <= 64 KB for 2 blocks; R7's 70.7 KB ran at
//   1 block/CU = 1.5 waves/SIMD. (2) v_mfma_32x32x16 ~= 32 cyc/SIMD (from
//   m119 2495 TF) -> MFMA-pipe floor ~51 us; we're at 23% of it (latency).
//   Changes:
//   - feat: [192][128] halfs + 16B-chunk XOR swizzle (chunk ^= pos&7). All
//     reads are 8-channel aligned -> swizzle exact; banks spread (<=4-way).
//     49,152 B (was 52,224).
//   - staging: 2 x 6 KB, depth-1 counted protocol: per chunk
//     {vmcnt(0) [waits DMA issued ~1 chunk ago => free]; s_barrier;
//      sched_barrier(0); issue DMA(c+1); compute(c)}. 12,288 B.
//   - total LDS 61,440 < R6's proven-2-block 62,976 -> 2 blocks/CU
//     guaranteed = 12 waves/CU = 3 waves/SIMD; feat-phase of one block
//     overlaps MFMA-phase of the other.
//   - c-loop as 4x8 (outer runtime, inner unrolled): vector idx compile-time,
//     ~4x smaller code (I$), bc reload at k==0.

typedef _Float16 half8  __attribute__((ext_vector_type(8)));
typedef float    f32x16 __attribute__((ext_vector_type(16)));

#define NORM 0.022097086912079608f   /* 1/(32*sqrt(2)) */
#define INV_SQRT3 0.5773502691896258f

// ---------------- prep: fragment-swizzled f16 weights, per-(t,u) interleave ----
// Ball[((t*32+u)*6 + slot)*512 + lane*8 + j]: lane n = lane&31, kq = lane>>5,
// kh = slot&1, k-channel v = kh*16 + kq*8 + j.
//   slot 0,1: NORM*W0[u][v][n]
//   slot 2,3: NORM*INV_SQRT3*W1[u][v][n]
//   slot 4,5: NORM*(W2[u][v][n] + W3[v][u][n])
__global__ void prep_kernel(const float* __restrict__ Wa, const float* __restrict__ Wb,
                            const float* __restrict__ Wc, const float* __restrict__ Wd,
                            _Float16* __restrict__ Ball) {
    int idx = blockIdx.x * 256 + threadIdx.x;   // 0..49151
    if (idx >= 49152) return;
    int lane = idx & 63;
    int frag = idx >> 6;          // 0..767, wave-uniform
    int slot = frag % 6;
    int tu   = frag / 6;
    int u = tu & 31, t = tu >> 5;
    int n = lane & 31, kq = lane >> 5;
    int kh = slot & 1, seg = slot >> 1;
    const float* Ws[4] = {Wa, Wb, Wc, Wd};
    const float* W = Ws[t];
    half8 out;
#pragma unroll
    for (int j = 0; j < 8; ++j) {
        int v = kh * 16 + kq * 8 + j;
        float val;
        if (seg == 0)      val = NORM * W[u * 1024 + v * 32 + n];
        else if (seg == 1) val = NORM * INV_SQRT3 * W[32768 + u * 1024 + v * 32 + n];
        else               val = NORM * (W[65536 + u * 1024 + v * 32 + n] +
                                         W[98304 + v * 1024 + u * 32 + n]);
        out[j] = (_Float16)val;
    }
    *(half8*)(Ball + (size_t)frag * 512 + lane * 8) = out;
}

// async global->LDS, 16B per lane. LDS dest = wave-uniform base + lane*16.
__device__ __forceinline__ void gload_lds16(const _Float16* g, _Float16* l) {
    __builtin_amdgcn_global_load_lds(
        (const __attribute__((address_space(1))) unsigned int*)g,
        (__attribute__((address_space(3))) unsigned int*)l, 16, 0, 0);
}

// ---------------- main kernel ----------------
// WG = 384 thr (6 waves) owns 32 batches = 192 positions; wave owns 32 (one M-tile).
// feat[pos][ch] pos-major, swizzled: half index = pos*128 + ((chgrp^(pos&7))<<3)+ (ch&7).
__launch_bounds__(384, 3)
__global__ void petp_main(const float* __restrict__ x,
                          const _Float16* __restrict__ Ball,
                          float* __restrict__ y) {
    __shared__ _Float16 feat[192 * 128];   // 49,152 B (XOR-swizzled 16B chunks)
    __shared__ _Float16 Bst[2][3072];      // 2 x 6 KB staging (chunk = 1 u-step)

    const int tid  = threadIdx.x;
    const int wave = tid >> 6;
    const int lane = tid & 63;
    const int mw = lane & 31;   // A row (position in tile) AND C/D col n
    const int q8 = lane >> 5;   // k-half within a K=16 MFMA
    const int wvu = __builtin_amdgcn_readfirstlane(wave);   // 0..5 = frag slot

    f32x16 acc_s;
    f32x16 acc_v[3];
#pragma unroll
    for (int r = 0; r < 16; ++r) {
        acc_s[r] = 0.f; acc_v[0][r] = 0.f; acc_v[1][r] = 0.f; acc_v[2][r] = 0.f;
    }

    const int wg = blockIdx.x;
    const float* xg = x + (size_t)wg * (192 * 128);

    const _Float16* fpos = feat + (wave * 32 + mw) * 128;
    const int px = mw & 7;   // pos&7 for my lane (wave*32 is 8-aligned)

    half8 sl_s[2];       // per-lane A-side k-slices, persistent per variant
    half8 sl_v[2][3];

#pragma unroll 1
    for (int t = 0; t < 4; ++t) {
        // all prior-variant readers of feat/Bst are done past this barrier
        __builtin_amdgcn_s_barrier();
        __builtin_amdgcn_sched_barrier(0);

        const _Float16* Bt = Ball + t * 98304;

        // prologue: DMA chunk 0 (lands during feat build)
        gload_lds16(Bt + wvu * 512 + lane * 8, &Bst[0][wvu * 512]);

        // ---- build variant-t features into swizzled pos-major LDS ----
#pragma unroll 2
        for (int it = 0; it < 11; ++it) {
            int item = it * 384 + tid;        // 32 batches x 128 channels
            if (item < 4096) {
                int b = item >> 7;
                int c = item & 127;
                const float* bp = xg + b * 768 + c;
                float v00 = bp[0],   v01 = bp[128], v02 = bp[256];
                float v10 = bp[384], v11 = bp[512], v12 = bp[640];
                float rs0 = v00 + v01 + v02, rs1 = v10 + v11 + v12;
                float cs0 = v00 + v10, cs1 = v01 + v11, cs2 = v02 + v12;
                float tot = rs0 + rs1;
                float xv[6] = {v00, v01, v02, v10, v11, v12};
                float rs[2] = {rs0, rs1};
                float cs[3] = {cs0, cs1, cs2};
                int row = (c < 32) ? c : 32 + ((c - 32) % 3) * 32 + (c - 32) / 3;
                int rhi = row >> 3, rlo = row & 7;
#pragma unroll
                for (int p6 = 0; p6 < 6; ++p6) {
                    int i = p6 / 3, j = p6 % 3;
                    float xvv = xv[p6];
                    float f;
                    if      (t == 0) f = xvv;
                    else if (t == 1) f = (rs[i] - xvv) * 0.5f;
                    else if (t == 2) f = cs[j] - xvv;
                    else             f = (tot - rs[i] - cs[j] + xvv) * 0.5f;
                    int pos = b * 6 + p6;
                    feat[pos * 128 + (((rhi ^ (pos & 7)) << 3) | rlo)] = (_Float16)f;
                }
            }
        }

        half8 bcS, bcG0, bcG1, bcG2;   // broadcast chunk: 8 u-values, registers

        // ---- 32 u-steps as 4 groups x 8; depth-1 DMA, free vmcnt(0) ----
#pragma unroll 1
        for (int cb = 0; cb < 4; ++cb) {
#pragma unroll
            for (int k = 0; k < 8; ++k) {
                // DMA(c) was issued one full chunk (~700cy) ago -> wait ~free.
                // k==0 adds lgkmcnt(0): feat ds_writes drained (needed at cb==0,
                // cheap otherwise).
                if (k == 0)
                    asm volatile("s_waitcnt vmcnt(0) lgkmcnt(0)" ::: "memory");
                else
                    asm volatile("s_waitcnt vmcnt(0)" ::: "memory");
                __builtin_amdgcn_s_barrier();
                __builtin_amdgcn_sched_barrier(0);   // raw s_barrier isn't a fence

                // issue DMA for chunk c+1 (buffer (c+1)&1: all waves finished
                // reading it in iter c-1, guaranteed by the barrier above)
                if (k < 7) {
                    int cn = cb * 8 + k + 1;
                    gload_lds16(Bt + (cn * 6 + wvu) * 512 + lane * 8,
                                &Bst[(k + 1) & 1][wvu * 512]);
                } else if (cb < 3) {
                    int cn = cb * 8 + 8;
                    gload_lds16(Bt + (cn * 6 + wvu) * 512 + lane * 8,
                                &Bst[0][wvu * 512]);
                }

                if (cb == 0 && k == 0) {   // per-lane A-side slices, once/variant
#pragma unroll
                    for (int kh = 0; kh < 2; ++kh) {
                        sl_s[kh] = *(const half8*)(fpos + (((kh * 2 + q8) ^ px) << 3));
#pragma unroll
                        for (int i = 0; i < 3; ++i)
                            sl_v[kh][i] = *(const half8*)(fpos + (((4 + i * 4 + kh * 2 + q8) ^ px) << 3));
                    }
                }
                if (k == 0) {   // broadcast chunk for u = cb*8 .. cb*8+7
                    bcS  = *(const half8*)(fpos + ((cb ^ px) << 3));
                    bcG0 = *(const half8*)(fpos + (((4 + cb) ^ px) << 3));
                    bcG1 = *(const half8*)(fpos + (((8 + cb) ^ px) << 3));
                    bcG2 = *(const half8*)(fpos + (((12 + cb) ^ px) << 3));
                }

                const _Float16* F = &Bst[k & 1][lane * 8];
                __builtin_amdgcn_s_setprio(1);
                {
                    half8 bA0 = *(const half8*)(F);
                    half8 bA1 = *(const half8*)(F + 512);
                    half8 bG0 = *(const half8*)(F + 1024);
                    half8 bG1 = *(const half8*)(F + 1536);
                    half8 bV0 = *(const half8*)(F + 2048);
                    half8 bV1 = *(const half8*)(F + 2560);
                    _Float16 su = bcS[k];
                    _Float16 g0 = bcG0[k], g1 = bcG1[k], g2 = bcG2[k];

                    half8 af;
                    // ---- ys: s.s^T ----
                    af = sl_s[0] * su;
                    acc_s = __builtin_amdgcn_mfma_f32_32x32x16_f16(af, bA0, acc_s, 0, 0, 0);
                    af = sl_s[1] * su;
                    acc_s = __builtin_amdgcn_mfma_f32_32x32x16_f16(af, bA1, acc_s, 0, 0, 0);
                    // ---- ys: Gram(v) ----
                    af = sl_v[0][0] * g0 + sl_v[0][1] * g1 + sl_v[0][2] * g2;
                    acc_s = __builtin_amdgcn_mfma_f32_32x32x16_f16(af, bG0, acc_s, 0, 0, 0);
                    af = sl_v[1][0] * g0 + sl_v[1][1] * g1 + sl_v[1][2] * g2;
                    acc_s = __builtin_amdgcn_mfma_f32_32x32x16_f16(af, bG1, acc_s, 0, 0, 0);
                    // ---- yv: s[u] v[v,kc], B2 shared across kc ----
#pragma unroll
                    for (int kc = 0; kc < 3; ++kc) {
                        half8 af0 = sl_v[0][kc] * su;
                        acc_v[kc] = __builtin_amdgcn_mfma_f32_32x32x16_f16(af0, bV0, acc_v[kc], 0, 0, 0);
                        half8 af1 = sl_v[1][kc] * su;
                        acc_v[kc] = __builtin_amdgcn_mfma_f32_32x32x16_f16(af1, bV1, acc_v[kc], 0, 0, 0);
                    }
                }
                __builtin_amdgcn_s_setprio(0);
            }
        }
    }

    // ---- epilogue: 32x32 C/D layout col(n)=lane&31, row=(reg&3)+8*(reg>>2)+4*q8 ----
    float* yg = y + (size_t)wg * (192 * 128);
    const int pb = wave * 32 + q8 * 4;
#pragma unroll
    for (int r = 0; r < 16; ++r) {
        int pos = pb + (r & 3) + 8 * (r >> 2);
        float* yp = yg + pos * 128;
        __builtin_nontemporal_store(acc_s[r], yp + mw);
        __builtin_nontemporal_store(acc_v[0][r], yp + 32 + 3 * mw + 0);
        __builtin_nontemporal_store(acc_v[1][r], yp + 32 + 3 * mw + 1);
        __builtin_nontemporal_store(acc_v[2][r], yp + 32 + 3 * mw + 2);
    }
}

extern "C" void kernel_launch(void* const* d_in, const int* in_sizes, int n_in,
                              void* d_out, int out_size, void* d_ws, size_t ws_size,
                              hipStream_t stream) {
    const float* x  = (const float*)d_in[0];
    const float* Wa = (const float*)d_in[1];
    const float* Wb = (const float*)d_in[2];
    const float* Wc = (const float*)d_in[3];
    const float* Wd = (const float*)d_in[4];
    float* y = (float*)d_out;

    _Float16* Ball = (_Float16*)d_ws;          // 393216 half = 768 KB

    int nbatch = in_sizes[0] / 768;            // 16384
    int nwg = nbatch / 32;                     // 512 = 2 blocks/CU exactly

    prep_kernel<<<192, 256, 0, stream>>>(Wa, Wb, Wc, Wd, Ball);
    petp_main<<<nwg, 384, 0, stream>>>(x, Ball, y);
}